// Round 5
// baseline (142.787 us; speedup 1.0000x reference)
//
#include <hip/hip_runtime.h>

// CrumbReconstructor: for each 8-float block of x, find nearest codebook row
// (squared Euclidean over 256 rows of length 8), output that row.
//
// R5: R4's TPK=7 never materialized -- compiler capped VGPRs at 64 (default
// 8-waves/SIMD budget) and restructured the key array away. Fix:
//   - TPK=4, block=64: 32 key regs + row(9) + state(12) ~= 60 VGPR, fits.
//   - __launch_bounds__(64, 4): explicitly allow up to 128 VGPR so the
//     compiler keeps all 4 keys resident (VGPR_Count is the diagnostic).
//   - 802816 = 3136 blocks x 64 thr x 4 keys EXACT; 12.25 blocks/CU -> 6% tail.
//   - norms read as float4 per 4-row group (halves the norm LDS traffic).
// Per-CU per-row: LDS ~27cyc/wave, VALU 4x13x2/4 SIMD -> both ~35us. 
// Hot-loop math bit-identical to R0 (absmax 0.0 in all rounds).

#define LBLK 8      // memblock length
#define NROW 256    // codebook rows
#define TPK 4       // key-blocks per thread
#define BLOCK 64    // threads per workgroup (1 wave)

__global__ __launch_bounds__(BLOCK, 4) void crumb_kernel(
    const float* __restrict__ x,
    const float* __restrict__ mem,
    float* __restrict__ out,
    int nblocks,
    int total_threads)
{
    __shared__ float s_mem[NROW * LBLK];   // 8 KB, rows contiguous
    __shared__ float s_norm[NROW];         // 1 KB, read as float4 groups

    const int tid = threadIdx.x;

    // --- stage codebook: 64 threads x 4 rows each ---
    {
        const float4* g = (const float4*)mem;
        #pragma unroll
        for (int r = 0; r < NROW / BLOCK; ++r) {
            int row = tid + r * BLOCK;
            float4 a = g[row * 2 + 0];
            float4 b = g[row * 2 + 1];
            ((float4*)s_mem)[row * 2 + 0] = a;
            ((float4*)s_mem)[row * 2 + 1] = b;
            // numpy order: elementwise square, 8-wide pairwise tree sum
            float q0 = a.x * a.x, q1 = a.y * a.y, q2 = a.z * a.z, q3 = a.w * a.w;
            float q4 = b.x * b.x, q5 = b.y * b.y, q6 = b.z * b.z, q7 = b.w * b.w;
            s_norm[row] = ((q0 + q1) + (q2 + q3)) + ((q4 + q5) + (q6 + q7));
        }
    }
    __syncthreads();

    const int g0 = blockIdx.x * BLOCK + tid;   // first key for this thread

    float k[TPK * LBLK];     // flat: keeps the compiler honest
    float knorm[TPK];
    long  kb[TPK];
    bool  valid[TPK];

    #pragma unroll
    for (int t = 0; t < TPK; ++t) {
        long b0 = (long)g0 + (long)t * total_threads;   // strided -> coalesced
        valid[t] = (b0 < (long)nblocks);
        kb[t] = valid[t] ? b0 : 0;
        const float4* g = (const float4*)(x + kb[t] * LBLK);
        float4 a = g[0], b = g[1];
        k[t*LBLK+0] = a.x; k[t*LBLK+1] = a.y; k[t*LBLK+2] = a.z; k[t*LBLK+3] = a.w;
        k[t*LBLK+4] = b.x; k[t*LBLK+5] = b.y; k[t*LBLK+6] = b.z; k[t*LBLK+7] = b.w;
        float q0 = a.x * a.x, q1 = a.y * a.y, q2 = a.z * a.z, q3 = a.w * a.w;
        float q4 = b.x * b.x, q5 = b.y * b.y, q6 = b.z * b.z, q7 = b.w * b.w;
        knorm[t] = ((q0 + q1) + (q2 + q3)) + ((q4 + q5) + (q6 + q7));
    }

    float best[TPK];
    int   bidx[TPK];
    #pragma unroll
    for (int t = 0; t < TPK; ++t) { best[t] = 3.4e38f; bidx[t] = 0; }

    // --- score all 256 rows, in groups of 4 (one float4 norm read/group) ---
    for (int grp = 0; grp < NROW / 4; ++grp) {
        float4 nr = ((const float4*)s_norm)[grp];
        #pragma unroll
        for (int mi = 0; mi < 4; ++mi) {
            const int m = grp * 4 + mi;
            float4 a = ((const float4*)s_mem)[m * 2 + 0];
            float4 b = ((const float4*)s_mem)[m * 2 + 1];
            const float nrm = (mi == 0) ? nr.x : (mi == 1) ? nr.y
                            : (mi == 2) ? nr.z : nr.w;

            #pragma unroll
            for (int t = 0; t < TPK; ++t) {
                // sequential FMA dot, bit-identical to R0 (absmax 0)
                float dot = k[t*LBLK+0] * a.x;
                dot = fmaf(k[t*LBLK+1], a.y, dot);
                dot = fmaf(k[t*LBLK+2], a.z, dot);
                dot = fmaf(k[t*LBLK+3], a.w, dot);
                dot = fmaf(k[t*LBLK+4], b.x, dot);
                dot = fmaf(k[t*LBLK+5], b.y, dot);
                dot = fmaf(k[t*LBLK+6], b.z, dot);
                dot = fmaf(k[t*LBLK+7], b.w, dot);
                float d = fmaf(dot, -2.0f, knorm[t]) + nrm;
                // strict < : first (lowest) index wins exact ties
                if (d < best[t]) { best[t] = d; bidx[t] = m; }
            }
        }
    }

    // --- gather winning rows from LDS, store ---
    #pragma unroll
    for (int t = 0; t < TPK; ++t) {
        if (valid[t]) {
            float4* o = (float4*)(out + kb[t] * LBLK);
            o[0] = ((const float4*)s_mem)[bidx[t] * 2 + 0];
            o[1] = ((const float4*)s_mem)[bidx[t] * 2 + 1];
        }
    }
}

extern "C" void kernel_launch(void* const* d_in, const int* in_sizes, int n_in,
                              void* d_out, int out_size, void* d_ws, size_t ws_size,
                              hipStream_t stream) {
    const float* x   = (const float*)d_in[0];
    const float* mem = (const float*)d_in[1];
    float* out = (float*)d_out;

    int n = in_sizes[0];            // total x elements
    int nblocks = n / LBLK;         // key-blocks (802816)
    int grid = (nblocks + BLOCK * TPK - 1) / (BLOCK * TPK);   // 3136 exact
    int total_threads = grid * BLOCK;

    hipLaunchKernelGGL(crumb_kernel, dim3(grid), dim3(BLOCK), 0, stream,
                       x, mem, out, nblocks, total_threads);
}